// Round 3
// baseline (30421.887 us; speedup 1.0000x reference)
//
#include <hip/hip_runtime.h>
#include <math.h>

constexpr int Bb  = 64;
constexpr int Tt  = 2048;
constexpr int INN = 128;
constexpr int HH  = 256;
constexpr int ROWS = Bb * Tt;   // 131072

// ---------------------------------------------------------------------------
// GEMM: out[row][j] = sum_k in[row][k] * W[j][k] + bias1[j] + bias2[j]
// rows = B*T, j < 256, K in {128, 256}. Tile: 64 rows x 256 cols, Kc=16,
// 256 threads, 8x8 register tile per thread. In-place safe (WG owns all 256
// cols of its 64 rows; reads of those rows complete before epilogue writes).
// ---------------------------------------------------------------------------
template <int K>
__global__ __launch_bounds__(256) void ih_gemm(const float* in, const float* W,
                                               const float* bias1, const float* bias2,
                                               float* out)
{
    __shared__ float a_lds[16][68];    // [kk][row]   (+4 pad)
    __shared__ float b_lds[16][264];   // [kk][col]   (+8 pad)

    const int tid = threadIdx.x;
    const int tx  = tid & 31;   // col group: cols tx*8 .. +8
    const int ty  = tid >> 5;   // row group: rows ty*8 .. +8
    const int row0 = blockIdx.x * 64;

    float acc[8][8];
#pragma unroll
    for (int r = 0; r < 8; ++r)
#pragma unroll
        for (int c = 0; c < 8; ++c) acc[r][c] = 0.f;

    for (int k0 = 0; k0 < K; k0 += 16) {
#pragma unroll
        for (int i = 0; i < 4; ++i) {
            int e = i * 256 + tid;
            int r = e >> 4, kk = e & 15;
            a_lds[kk][r] = in[(row0 + r) * K + k0 + kk];
        }
#pragma unroll
        for (int i = 0; i < 16; ++i) {
            int e = i * 256 + tid;
            int j = e >> 4, kk = e & 15;
            b_lds[kk][j] = W[j * K + k0 + kk];
        }
        __syncthreads();

#pragma unroll
        for (int kk = 0; kk < 16; ++kk) {
            float4 a0 = *(const float4*)&a_lds[kk][ty * 8];
            float4 a1 = *(const float4*)&a_lds[kk][ty * 8 + 4];
            float4 b0 = *(const float4*)&b_lds[kk][tx * 8];
            float4 b1 = *(const float4*)&b_lds[kk][tx * 8 + 4];
            float av[8] = {a0.x, a0.y, a0.z, a0.w, a1.x, a1.y, a1.z, a1.w};
            float bv[8] = {b0.x, b0.y, b0.z, b0.w, b1.x, b1.y, b1.z, b1.w};
#pragma unroll
            for (int r = 0; r < 8; ++r)
#pragma unroll
                for (int c = 0; c < 8; ++c)
                    acc[r][c] += av[r] * bv[c];
        }
        __syncthreads();
    }

    float bsum[8];
#pragma unroll
    for (int c = 0; c < 8; ++c) {
        int j = tx * 8 + c;
        bsum[c] = bias1[j] + bias2[j];
    }
#pragma unroll
    for (int r = 0; r < 8; ++r) {
        int row = row0 + ty * 8 + r;
        float4 o0 = make_float4(acc[r][0] + bsum[0], acc[r][1] + bsum[1],
                                acc[r][2] + bsum[2], acc[r][3] + bsum[3]);
        float4 o1 = make_float4(acc[r][4] + bsum[4], acc[r][5] + bsum[5],
                                acc[r][6] + bsum[6], acc[r][7] + bsum[7]);
        *(float4*)&out[row * HH + tx * 8]     = o0;
        *(float4*)&out[row * HH + tx * 8 + 4] = o1;
    }
}

// ---------------------------------------------------------------------------
// Recurrence, output-stationary. In-place over xp: h_t = tanh(xp[t] + W@h).
// One WG per batch, 1024 thr = 16 waves. Lane owns output j = 16w + (l&15),
// k-quarter q = l>>4 (k in [64q, 64q+64)): 64 weight VGPRs per lane, each
// (j,k) covered exactly once.
//   - h lives in LDS, double-buffered (read hb[t&1], write hb[(t+1)&1]) ->
//     exactly ONE barrier per step (double buffer removes the WAR hazard)
//   - matvec: 16x float4 broadcast LDS reads + 64 FMA per lane
//   - reduction IN-WAVE only: shfl_xor(16) + shfl_xor(32) — the 4 replica
//     lanes of each j then all hold the full sum; q==0 lane commits
//   - h LDS layout chunk-skewed: k -> 68*(k>>6) + (k&63), so the 4 q-groups'
//     broadcast reads hit disjoint banks (4q+4c..+3) — conflict-free
//   - fast tanh: 1 - 2*rcp(exp(2s)+1); xp[t+1] prefetched one step ahead
// ---------------------------------------------------------------------------
__global__ __launch_bounds__(1024) void rnn_recur(float* xp, const float* Whh)
{
    __shared__ float hb[2][272];           // skewed: 4 chunks of 68 (64 + 4 pad)

    const int tid = threadIdx.x;
    const int w   = tid >> 6;              // wave -> output block [16w, 16w+16)
    const int l   = tid & 63;
    const int j   = 16 * w + (l & 15);     // output this lane accumulates
    const int q   = l >> 4;                // k-quarter: k in [64q, 64q+64)
    float* xpb = xp + (size_t)blockIdx.x * Tt * HH;

    // weights: wreg4[c] = Whh[j*HH + 64q + 4c .. +3]   (64 VGPRs, loaded once)
    float4 wreg4[16];
    {
        const float4* wp = (const float4*)&Whh[j * HH + 64 * q];
#pragma unroll
        for (int c = 0; c < 16; ++c) wreg4[c] = wp[c];
    }

    if (tid < HH) hb[0][68 * (tid >> 6) + (tid & 63)] = 0.f;
    float xv = xpb[j];                     // xp[t=0][j] (4 replica lanes/j, same value)
    __syncthreads();

#pragma unroll 1
    for (int t = 0; t < Tt; ++t) {
        // prefetch next step's xp (one full step of latency hiding)
        int tn = (t + 1 < Tt) ? (t + 1) : t;
        float xnext = xpb[tn * HH + j];

        // matvec over this lane's k-quarter (broadcast b128 reads, skewed)
        const float* hq = &hb[t & 1][68 * q];
        float acc = 0.f;
#pragma unroll 4
        for (int c = 0; c < 16; ++c) {
            float4 h4 = *(const float4*)&hq[4 * c];
            float4 wv = wreg4[c];
            acc = fmaf(wv.x, h4.x, acc);
            acc = fmaf(wv.y, h4.y, acc);
            acc = fmaf(wv.z, h4.z, acc);
            acc = fmaf(wv.w, h4.w, acc);
        }

        // in-wave reduction across the 4 k-quarters of this j
        acc += __shfl_xor(acc, 16, 64);
        acc += __shfl_xor(acc, 32, 64);
        float s = acc + xv;

        // fast tanh: 1 - 2/(exp(2s)+1); saturates correctly at +/-inf
        float e  = __expf(2.f * s);
        float hn = 1.f - 2.f * __builtin_amdgcn_rcpf(e + 1.f);

        // q==0 replica commits h_t (LDS next buffer + global, off critical path)
        if (q == 0) {
            hb[(t + 1) & 1][68 * (j >> 6) + (j & 63)] = hn;
            xpb[t * HH + j] = hn;          // in-place: xp[t] consumed at t-1
        }
        __syncthreads();                   // the ONLY barrier per step
        xv = xnext;
    }
}

// ---------------------------------------------------------------------------
// FC: out[b] = dot(h2[b][T-1][:], W_fc) + b_fc.  One wave per batch.
// ---------------------------------------------------------------------------
__global__ __launch_bounds__(64) void fc_kernel(const float* h2, const float* Wfc,
                                                const float* bfc, float* out)
{
    const int b = blockIdx.x;
    const int l = threadIdx.x;
    const float* hrow = h2 + ((size_t)b * Tt + (Tt - 1)) * HH;
    float4 hv = *(const float4*)&hrow[4 * l];
    float4 wv = *(const float4*)&Wfc[4 * l];
    float p = hv.x * wv.x + hv.y * wv.y + hv.z * wv.z + hv.w * wv.w;
#pragma unroll
    for (int off = 32; off > 0; off >>= 1) p += __shfl_down(p, off, 64);
    if (l == 0) out[b] = p + bfc[0];
}

// ---------------------------------------------------------------------------
extern "C" void kernel_launch(void* const* d_in, const int* in_sizes, int n_in,
                              void* d_out, int out_size, void* d_ws, size_t ws_size,
                              hipStream_t stream)
{
    const float* x     = (const float*)d_in[0];
    const float* W_ih0 = (const float*)d_in[1];
    const float* W_hh0 = (const float*)d_in[2];
    const float* b_ih0 = (const float*)d_in[3];
    const float* b_hh0 = (const float*)d_in[4];
    const float* W_ih1 = (const float*)d_in[5];
    const float* W_hh1 = (const float*)d_in[6];
    const float* b_ih1 = (const float*)d_in[7];
    const float* b_hh1 = (const float*)d_in[8];
    const float* W_fc  = (const float*)d_in[9];
    const float* b_fc  = (const float*)d_in[10];
    float* ws  = (float*)d_ws;                 // B*T*H floats (128 MiB)
    float* out = (float*)d_out;

    ih_gemm<INN><<<ROWS / 64, 256, 0, stream>>>(x, W_ih0, b_ih0, b_hh0, ws);
    rnn_recur<<<Bb, 1024, 0, stream>>>(ws, W_hh0);
    ih_gemm<HH><<<ROWS / 64, 256, 0, stream>>>(ws, W_ih1, b_ih1, b_hh1, ws);
    rnn_recur<<<Bb, 1024, 0, stream>>>(ws, W_hh1);
    fc_kernel<<<Bb, 64, 0, stream>>>(ws, W_fc, b_fc, out);
}

// Round 4
// 3596.833 us; speedup vs baseline: 8.4580x; 8.4580x over previous
//
#include <hip/hip_runtime.h>
#include <math.h>

constexpr int Bb  = 64;
constexpr int Tt  = 2048;
constexpr int INN = 128;
constexpr int HH  = 256;
constexpr int ROWS = Bb * Tt;   // 131072

// ---------------------------------------------------------------------------
// GEMM: out[row][j] = sum_k in[row][k] * W[j][k] + bias1[j] + bias2[j]
// rows = B*T, j < 256, K in {128, 256}. Tile: 64 rows x 256 cols, Kc=16,
// 256 threads, 8x8 register tile per thread. In-place safe (WG owns all 256
// cols of its 64 rows; reads of those rows complete before epilogue writes).
// ---------------------------------------------------------------------------
template <int K>
__global__ __launch_bounds__(256) void ih_gemm(const float* in, const float* W,
                                               const float* bias1, const float* bias2,
                                               float* out)
{
    __shared__ float a_lds[16][68];    // [kk][row]   (+4 pad)
    __shared__ float b_lds[16][264];   // [kk][col]   (+8 pad)

    const int tid = threadIdx.x;
    const int tx  = tid & 31;   // col group: cols tx*8 .. +8
    const int ty  = tid >> 5;   // row group: rows ty*8 .. +8
    const int row0 = blockIdx.x * 64;

    float acc[8][8];
#pragma unroll
    for (int r = 0; r < 8; ++r)
#pragma unroll
        for (int c = 0; c < 8; ++c) acc[r][c] = 0.f;

    for (int k0 = 0; k0 < K; k0 += 16) {
#pragma unroll
        for (int i = 0; i < 4; ++i) {
            int e = i * 256 + tid;
            int r = e >> 4, kk = e & 15;
            a_lds[kk][r] = in[(row0 + r) * K + k0 + kk];
        }
#pragma unroll
        for (int i = 0; i < 16; ++i) {
            int e = i * 256 + tid;
            int j = e >> 4, kk = e & 15;
            b_lds[kk][j] = W[j * K + k0 + kk];
        }
        __syncthreads();

#pragma unroll
        for (int kk = 0; kk < 16; ++kk) {
            float4 a0 = *(const float4*)&a_lds[kk][ty * 8];
            float4 a1 = *(const float4*)&a_lds[kk][ty * 8 + 4];
            float4 b0 = *(const float4*)&b_lds[kk][tx * 8];
            float4 b1 = *(const float4*)&b_lds[kk][tx * 8 + 4];
            float av[8] = {a0.x, a0.y, a0.z, a0.w, a1.x, a1.y, a1.z, a1.w};
            float bv[8] = {b0.x, b0.y, b0.z, b0.w, b1.x, b1.y, b1.z, b1.w};
#pragma unroll
            for (int r = 0; r < 8; ++r)
#pragma unroll
                for (int c = 0; c < 8; ++c)
                    acc[r][c] += av[r] * bv[c];
        }
        __syncthreads();
    }

    float bsum[8];
#pragma unroll
    for (int c = 0; c < 8; ++c) {
        int j = tx * 8 + c;
        bsum[c] = bias1[j] + bias2[j];
    }
#pragma unroll
    for (int r = 0; r < 8; ++r) {
        int row = row0 + ty * 8 + r;
        float4 o0 = make_float4(acc[r][0] + bsum[0], acc[r][1] + bsum[1],
                                acc[r][2] + bsum[2], acc[r][3] + bsum[3]);
        float4 o1 = make_float4(acc[r][4] + bsum[4], acc[r][5] + bsum[5],
                                acc[r][6] + bsum[6], acc[r][7] + bsum[7]);
        *(float4*)&out[row * HH + tx * 8]     = o0;
        *(float4*)&out[row * HH + tx * 8 + 4] = o1;
    }
}

// ---------------------------------------------------------------------------
// Recurrence, output-stationary. In-place over xp: h_t = tanh(xp[t] + W@h).
// One WG per batch, 1024 thr = 16 waves. Lane owns output j = 16w + (l&15),
// k-quarter q = l>>4 (k in [64q, 64q+64)): 64 weight VGPRs per lane.
//   - ALL inner loops FULLY unrolled: compile-time indices into wreg4 keep it
//     in the register file (R2's "#pragma unroll 4" demoted it to scratch:
//     VGPR 36, +24 MB HBM traffic, 7x slowdown)
//   - h in LDS, double-buffered -> ONE barrier per step (no WAR hazard)
//   - reduction in-wave only: shfl_xor(16) + shfl_xor(32)
//   - h layout chunk-skewed (68*q + k) so the 4 q-groups hit disjoint banks
//   - fast tanh: 1 - 2*rcp(exp(2s)+1); xp[t+1] prefetched one step ahead
// ---------------------------------------------------------------------------
__global__ __launch_bounds__(1024) void rnn_recur(float* xp, const float* Whh)
{
    __shared__ float hb[2][272];           // skewed: 4 chunks of 68 (64 + 4 pad)

    const int tid = threadIdx.x;
    const int w   = tid >> 6;              // wave -> output block [16w, 16w+16)
    const int l   = tid & 63;
    const int j   = 16 * w + (l & 15);     // output this lane accumulates
    const int q   = l >> 4;                // k-quarter: k in [64q, 64q+64)
    float* xpb = xp + (size_t)blockIdx.x * Tt * HH;

    // weights: wreg4[c] = Whh[j*HH + 64q + 4c .. +3] — loaded with constant
    // indices (fully unrolled) so the array stays in registers.
    const float4* wp = (const float4*)&Whh[j * HH + 64 * q];
    float4 w0  = wp[0],  w1  = wp[1],  w2  = wp[2],  w3  = wp[3];
    float4 w4  = wp[4],  w5  = wp[5],  w6  = wp[6],  w7  = wp[7];
    float4 w8  = wp[8],  w9  = wp[9],  w10 = wp[10], w11 = wp[11];
    float4 w12 = wp[12], w13 = wp[13], w14 = wp[14], w15 = wp[15];

    if (tid < HH) hb[0][68 * (tid >> 6) + (tid & 63)] = 0.f;
    float xv = xpb[j];                     // xp[t=0][j] (4 replica lanes/j)
    __syncthreads();

#pragma unroll 1
    for (int t = 0; t < Tt; ++t) {
        // prefetch next step's xp (one full step of latency hiding)
        int tn = (t + 1 < Tt) ? (t + 1) : t;
        float xnext = xpb[tn * HH + j];

        // matvec over this lane's k-quarter — fully unrolled, registers only
        const float* hq = &hb[t & 1][68 * q];
        float4 h0, h1, h2, h3;
        float acc0 = 0.f, acc1 = 0.f, acc2 = 0.f, acc3 = 0.f;
#define MV4(HV, WV)                                                            \
        acc0 = fmaf((WV).x, (HV).x, acc0);                                     \
        acc1 = fmaf((WV).y, (HV).y, acc1);                                     \
        acc2 = fmaf((WV).z, (HV).z, acc2);                                     \
        acc3 = fmaf((WV).w, (HV).w, acc3);
        h0 = *(const float4*)&hq[0];
        h1 = *(const float4*)&hq[4];
        h2 = *(const float4*)&hq[8];
        h3 = *(const float4*)&hq[12];
        MV4(h0, w0)  MV4(h1, w1)  MV4(h2, w2)  MV4(h3, w3)
        h0 = *(const float4*)&hq[16];
        h1 = *(const float4*)&hq[20];
        h2 = *(const float4*)&hq[24];
        h3 = *(const float4*)&hq[28];
        MV4(h0, w4)  MV4(h1, w5)  MV4(h2, w6)  MV4(h3, w7)
        h0 = *(const float4*)&hq[32];
        h1 = *(const float4*)&hq[36];
        h2 = *(const float4*)&hq[40];
        h3 = *(const float4*)&hq[44];
        MV4(h0, w8)  MV4(h1, w9)  MV4(h2, w10) MV4(h3, w11)
        h0 = *(const float4*)&hq[48];
        h1 = *(const float4*)&hq[52];
        h2 = *(const float4*)&hq[56];
        h3 = *(const float4*)&hq[60];
        MV4(h0, w12) MV4(h1, w13) MV4(h2, w14) MV4(h3, w15)
#undef MV4
        float acc = (acc0 + acc1) + (acc2 + acc3);

        // in-wave reduction across the 4 k-quarters of this j
        acc += __shfl_xor(acc, 16, 64);
        acc += __shfl_xor(acc, 32, 64);
        float s = acc + xv;

        // fast tanh: 1 - 2/(exp(2s)+1); saturates correctly at +/-inf
        float e  = __expf(2.f * s);
        float hn = 1.f - 2.f * __builtin_amdgcn_rcpf(e + 1.f);

        // q==0 replica commits h_t (LDS next buffer + global)
        if (q == 0) {
            hb[(t + 1) & 1][68 * (j >> 6) + (j & 63)] = hn;
            xpb[t * HH + j] = hn;          // in-place: xp[t] consumed at t-1
        }
        __syncthreads();                   // the ONLY barrier per step
        xv = xnext;
    }
}

// ---------------------------------------------------------------------------
// FC: out[b] = dot(h2[b][T-1][:], W_fc) + b_fc.  One wave per batch.
// ---------------------------------------------------------------------------
__global__ __launch_bounds__(64) void fc_kernel(const float* h2, const float* Wfc,
                                                const float* bfc, float* out)
{
    const int b = blockIdx.x;
    const int l = threadIdx.x;
    const float* hrow = h2 + ((size_t)b * Tt + (Tt - 1)) * HH;
    float4 hv = *(const float4*)&hrow[4 * l];
    float4 wv = *(const float4*)&Wfc[4 * l];
    float p = hv.x * wv.x + hv.y * wv.y + hv.z * wv.z + hv.w * wv.w;
#pragma unroll
    for (int off = 32; off > 0; off >>= 1) p += __shfl_down(p, off, 64);
    if (l == 0) out[b] = p + bfc[0];
}

// ---------------------------------------------------------------------------
extern "C" void kernel_launch(void* const* d_in, const int* in_sizes, int n_in,
                              void* d_out, int out_size, void* d_ws, size_t ws_size,
                              hipStream_t stream)
{
    const float* x     = (const float*)d_in[0];
    const float* W_ih0 = (const float*)d_in[1];
    const float* W_hh0 = (const float*)d_in[2];
    const float* b_ih0 = (const float*)d_in[3];
    const float* b_hh0 = (const float*)d_in[4];
    const float* W_ih1 = (const float*)d_in[5];
    const float* W_hh1 = (const float*)d_in[6];
    const float* b_ih1 = (const float*)d_in[7];
    const float* b_hh1 = (const float*)d_in[8];
    const float* W_fc  = (const float*)d_in[9];
    const float* b_fc  = (const float*)d_in[10];
    float* ws  = (float*)d_ws;                 // B*T*H floats (128 MiB)
    float* out = (float*)d_out;

    ih_gemm<INN><<<ROWS / 64, 256, 0, stream>>>(x, W_ih0, b_ih0, b_hh0, ws);
    rnn_recur<<<Bb, 1024, 0, stream>>>(ws, W_hh0);
    ih_gemm<HH><<<ROWS / 64, 256, 0, stream>>>(ws, W_ih1, b_ih1, b_hh1, ws);
    rnn_recur<<<Bb, 1024, 0, stream>>>(ws, W_hh1);
    fc_kernel<<<Bb, 64, 0, stream>>>(ws, W_fc, b_fc, out);
}